// Round 14
// baseline (126.368 us; speedup 1.0000x reference)
//
#include <hip/hip_runtime.h>
#include <hip/hip_bf16.h>
#include <math.h>

#define B 4
#define T 128
#define C 512
#define NH 8
#define HS 64
#define BH (B*NH)   // 32

typedef __attribute__((ext_vector_type(8))) short bf16x8;
typedef __attribute__((ext_vector_type(4))) float f32x4;

__device__ __forceinline__ unsigned short bfc(float x) {
    return __builtin_bit_cast(unsigned short, __float2bfloat16(x));
}
__device__ __forceinline__ unsigned int pk_bf16(float a, float b) {
    return (unsigned int)bfc(a) | ((unsigned int)bfc(b) << 16);
}
__device__ __forceinline__ float lo_f(unsigned int g) {
    return __builtin_bit_cast(float, g << 16);
}
__device__ __forceinline__ float hi_f(unsigned int g) {
    return __builtin_bit_cast(float, g & 0xffff0000u);
}

// ---------------- K1: p{0,1} = X @ Wp{0,1}; z==2 computes p2, emits rr + V1T only.
// B staged to LDS transposed+converted directly (2 barriers/k-iter); A in-register from X.
// z==1 epilogue emits V0T = (p1@Wv0)^T; z==2 epilogue emits V1T = (p2@Wv1)^T.
__global__ __launch_bounds__(256) void proj_kernel(
    const float* __restrict__ X,
    const float* __restrict__ Wp0, const float* __restrict__ Wp1, const float* __restrict__ Wp2,
    const float* __restrict__ Wv0, const float* __restrict__ Wv1,
    unsigned short* __restrict__ p0b, unsigned short* __restrict__ p1b,
    unsigned short* __restrict__ V0T, unsigned short* __restrict__ V1T,
    float* __restrict__ rr)
{
    __shared__ __align__(16) unsigned short As[32][72];   // V-epilogue only
    __shared__ __align__(16) unsigned short Bs[64][72];   // B^T bf16 [n][k]
    __shared__ float sRS[4][32];
    const int z = blockIdx.z;
    const float* W = (z == 0) ? Wp0 : (z == 1) ? Wp1 : Wp2;
    const int m0 = blockIdx.y * 32, n0 = blockIdx.x * 64;
    const int tid = threadIdx.x;
    const int w = tid >> 6, lane = tid & 63, quad = lane >> 4, l16 = lane & 15;
    f32x4 acc[2];
    #pragma unroll
    for (int mt = 0; mt < 2; ++mt) acc[mt] = (f32x4){0.f, 0.f, 0.f, 0.f};

    const float* xr0 = X + (size_t)(m0 + l16) * 512;
    const float* xr1 = X + (size_t)(m0 + 16 + l16) * 512;

    for (int k0 = 0; k0 < 512; k0 += 64) {
        __syncthreads();                                   // drain prev MFMA reads of Bs
        // stage W tile transposed+converted: Bs[n][k] = bf16(W[k0+k][n0+n])
        #pragma unroll
        for (int it = 0; it < 4; ++it) {
            const int q = tid + it * 256;
            const int row = q >> 4, c4 = (q & 15) * 4;     // row = k local, c4 = n local
            const float4 v = *(const float4*)&W[(size_t)(k0 + row) * 512 + n0 + c4];
            Bs[c4 + 0][row] = bfc(v.x); Bs[c4 + 1][row] = bfc(v.y);
            Bs[c4 + 2][row] = bfc(v.z); Bs[c4 + 3][row] = bfc(v.w);
        }
        __syncthreads();                                   // Bs ready
        #pragma unroll
        for (int kt = 0; kt < 2; ++kt) {
            const int kb = k0 + kt * 32 + quad * 8;
            const bf16x8 b8 = *(const bf16x8*)&Bs[w * 16 + l16][kt * 32 + quad * 8];
            #pragma unroll
            for (int mt = 0; mt < 2; ++mt) {
                const float* xr = mt ? xr1 : xr0;
                const float4 a0 = *(const float4*)&xr[kb];
                const float4 a1 = *(const float4*)&xr[kb + 4];
                uint4 oa;
                oa.x = pk_bf16(a0.x, a0.y); oa.y = pk_bf16(a0.z, a0.w);
                oa.z = pk_bf16(a1.x, a1.y); oa.w = pk_bf16(a1.z, a1.w);
                acc[mt] = __builtin_amdgcn_mfma_f32_16x16x32_bf16(
                    __builtin_bit_cast(bf16x8, oa), b8, acc[mt], 0, 0, 0);
            }
        }
    }

    // store p0/p1 (p2 never materialized)
    if (z != 2) {
        const int n = n0 + w * 16 + l16;
        const int h = n >> 6, d = n & 63;
        unsigned short* pz = (z == 0) ? p0b : p1b;
        #pragma unroll
        for (int mt = 0; mt < 2; ++mt) {
            #pragma unroll
            for (int r = 0; r < 4; ++r) {
                const int m = m0 + mt * 16 + quad * 4 + r;
                const int bb = m >> 7, t = m & 127;
                pz[((size_t)(bb * NH + h) * T + t) * HS + d] = bfc(acc[mt][r]);
            }
        }
    }
    if (z == 2) {
        // rr = rowsums of p2
        #pragma unroll
        for (int mt = 0; mt < 2; ++mt)
            #pragma unroll
            for (int r = 0; r < 4; ++r) {
                float v = acc[mt][r];
                v += __shfl_xor(v, 1, 64); v += __shfl_xor(v, 2, 64);
                v += __shfl_xor(v, 4, 64); v += __shfl_xor(v, 8, 64);
                if (l16 == 0) sRS[w][mt * 16 + quad * 4 + r] = v;
            }
        __syncthreads();
        if (tid < 32) {
            const float s = sRS[0][tid] + sRS[1][tid] + sRS[2][tid] + sRS[3][tid];
            const int m = m0 + tid, bb = m >> 7, tl = m & 127, h = n0 >> 6;
            rr[(bb * NH + h) * T + tl] = s;
        }
    }

    // ---- V-epilogue (z==1: V0T from p1; z==2: V1T from p2) ----
    if (z >= 1) {
        const float* Wv = (z == 1) ? Wv0 : Wv1;
        unsigned short* VT = (z == 1) ? V0T : V1T;
        __syncthreads();                                   // drain main-loop Bs reads
        // stage acc -> As as [t][d] bf16
        #pragma unroll
        for (int mt = 0; mt < 2; ++mt)
            #pragma unroll
            for (int r = 0; r < 4; ++r)
                As[mt * 16 + quad * 4 + r][w * 16 + l16] = bfc(acc[mt][r]);
        // stage Wv^T -> Bs as [d'][d] bf16
        #pragma unroll
        for (int it = 0; it < 4; ++it) {
            const int k = (tid >> 4) + it * 16;
            const int d0 = (tid & 15) * 4;
            const float4 wv = *(const float4*)&Wv[(size_t)k * 64 + d0];
            Bs[d0 + 0][k] = bfc(wv.x); Bs[d0 + 1][k] = bfc(wv.y);
            Bs[d0 + 2][k] = bfc(wv.z); Bs[d0 + 3][k] = bfc(wv.w);
        }
        __syncthreads();
        f32x4 vacc[2];
        #pragma unroll
        for (int mt = 0; mt < 2; ++mt) vacc[mt] = (f32x4){0.f, 0.f, 0.f, 0.f};
        #pragma unroll
        for (int kt = 0; kt < 2; ++kt) {
            const bf16x8 b8 = *(const bf16x8*)&Bs[w * 16 + l16][kt * 32 + quad * 8];
            #pragma unroll
            for (int mt = 0; mt < 2; ++mt) {
                const bf16x8 a8 = *(const bf16x8*)&As[mt * 16 + l16][kt * 32 + quad * 8];
                vacc[mt] = __builtin_amdgcn_mfma_f32_16x16x32_bf16(a8, b8, vacc[mt], 0, 0, 0);
            }
        }
        // D[m=t][n=d']: col=l16 -> d' = w*16+l16 ; row = quad*4+r -> t local; store VT[d'][t]
        const int h = n0 >> 6;
        const int bb = m0 >> 7, t0 = m0 & 127;
        const int bh = bb * NH + h;
        const int dp = w * 16 + l16;
        #pragma unroll
        for (int mt = 0; mt < 2; ++mt) {
            uint2 o;
            o.x = pk_bf16(vacc[mt][0], vacc[mt][1]);
            o.y = pk_bf16(vacc[mt][2], vacc[mt][3]);
            *(uint2*)&VT[((size_t)bh * HS + dp) * T + t0 + mt * 16 + quad * 4] = o;
        }
    }
}

// ---------------- K2: attention; 512 blocks x 512 threads; V0T/V1T precomputed -> 2 barriers total
__global__ __launch_bounds__(512, 4) void attn_kernel(
    const unsigned short* __restrict__ p0b, const unsigned short* __restrict__ p1b,
    const float* __restrict__ rr,
    const unsigned short* __restrict__ V0Tg, const unsigned short* __restrict__ V1Tg,
    unsigned short* __restrict__ Yb)
{
    __shared__ __align__(16) unsigned short sV0T[64][136];
    __shared__ __align__(16) unsigned short sV1T[64][136];
    __shared__ float sS[8][128];
    __shared__ float srr[128];
    __shared__ float sZarr[8][8];            // [qq][wave] Z partials
    __shared__ float sY[8][8][64];           // [qq][wave][d] y partials

    const int bid = blockIdx.x;
    const int bh = bid & (BH - 1);
    const int ig = bid >> 5;                 // 0..15
    const int tid = threadIdx.x;
    const int w = tid >> 6;                  // 0..7 : wave owns row-tile mt = w
    const int lane = tid & 63;
    const int quad = lane >> 4;
    const int l16 = lane & 15;

    if (tid < 128) srr[tid] = rr[bh * T + tid];

    // ---- copy V0T/V1T tiles (bh slice, [d][t] bf16, 16 KB each): 64 rows x 16 chunks ----
    #pragma unroll
    for (int it = 0; it < 2; ++it) {
        const int q = tid + it * 512;        // 0..1023
        const int row = q >> 4, c8 = (q & 15) * 8;
        *(uint4*)&sV0T[row][c8] = *(const uint4*)&V0Tg[((size_t)bh * HS + row) * T + c8];
        *(uint4*)&sV1T[row][c8] = *(const uint4*)&V1Tg[((size_t)bh * HS + row) * T + c8];
    }

    // ---- all 8 S rows (wave w covers j = w*16+l16) ----
    {
        const int qr = l16 & 7;
        const int irow = (qr & 1) ? (16 * qr + 15 - ig) : (16 * qr + ig);
        const unsigned short* ap = p0b + ((size_t)bh * T + irow) * HS + (quad << 3);
        const unsigned short* bp = p1b + (size_t)bh * T * HS + (quad << 3);
        f32x4 s0 = (f32x4){0.f, 0.f, 0.f, 0.f};
        #pragma unroll
        for (int kt = 0; kt < 2; ++kt) {
            const bf16x8 a8 = *(const bf16x8*)(ap + (kt << 5));
            const bf16x8 b0 = *(const bf16x8*)(bp + (size_t)((w << 4) + l16) * HS + (kt << 5));
            s0 = __builtin_amdgcn_mfma_f32_16x16x32_bf16(a8, b0, s0, 0, 0, 0);
        }
        if (quad < 2) {
            #pragma unroll
            for (int r = 0; r < 4; ++r)
                sS[quad * 4 + r][(w << 4) + l16] = s0[r] * 0.125f;
        }
    }
    // zero partial buffers
    #pragma unroll
    for (int it = 0; it < 8; ++it) ((float*)sY)[tid + it * 512] = 0.f;
    if (tid < 64) ((float*)sZarr)[tid] = 0.f;
    __syncthreads();                                       // bar1: everything staged

    const float L2E = 1.4426950408889634f;

    // ---- hoisted global mhat (upper bound via shift-invariance) ----
    float mhat;
    {
        float aS = 0.f;
        #pragma unroll
        for (int q = 0; q < 8; ++q) {
            aS = fmaxf(aS, fabsf(sS[q][lane]));
            aS = fmaxf(aS, fabsf(sS[q][64 + lane]));
        }
        float aR = fmaxf(fabsf(srr[lane]), fabsf(srr[64 + lane]));
        #pragma unroll
        for (int off = 32; off; off >>= 1) {
            aS = fmaxf(aS, __shfl_xor(aS, off, 64));
            aR = fmaxf(aR, __shfl_xor(aR, off, 64));
        }
        mhat = aS * aR;
    }
    const float bexp = -mhat * L2E;
    const int jrow = (w << 4) + l16;
    const int ktmax = w >> 1;

    // ---- BARRIER-FREE loop: wave w participates in qq >= w (mtmax == qq) ----
    for (int qq = 7; qq >= w; --qq) {
        const int i = (qq & 1) ? (16 * qq + 15 - ig) : (16 * qq + ig);
        const float aL = sS[qq][jrow] * L2E;
        const bool rowok = (jrow <= i);
        f32x4 acc[4];
        #pragma unroll
        for (int dt = 0; dt < 4; ++dt) acc[dt] = (f32x4){0.f, 0.f, 0.f, 0.f};
        float zacc = 0.f;

        for (int kt = 0; kt <= ktmax; ++kt) {
            const int kbase = (kt << 5) + (quad << 3);
            float rk[8];
            *(float4*)&rk[0] = *(const float4*)&srr[kbase];
            *(float4*)&rk[4] = *(const float4*)&srr[kbase + 4];
            const int dlim = rowok ? (jrow - kbase) : -1;
            float e[8];
            #pragma unroll
            for (int q = 0; q < 8; ++q) {
                const float ex = __builtin_amdgcn_exp2f(fmaf(aL, rk[q], bexp));
                e[q] = (q <= dlim) ? ex : 0.f;
                zacc += e[q];
            }
            uint4 o;
            o.x = pk_bf16(e[0], e[1]);
            o.y = pk_bf16(e[2], e[3]);
            o.z = pk_bf16(e[4], e[5]);
            o.w = pk_bf16(e[6], e[7]);
            const bf16x8 a8 = __builtin_bit_cast(bf16x8, o);
            #pragma unroll
            for (int dt = 0; dt < 4; ++dt) {
                const bf16x8 b8 = *(const bf16x8*)&sV1T[(dt << 4) + l16][(quad << 3) + (kt << 5)];
                acc[dt] = __builtin_amdgcn_mfma_f32_16x16x32_bf16(a8, b8, acc[dt], 0, 0, 0);
            }
        }

        // ---- epilogue: partial y over this wave's row-tile, all 4 d-tiles ----
        float part[4];
        #pragma unroll
        for (int dt = 0; dt < 4; ++dt) {
            const uint2 uu = *(const uint2*)&sV0T[(dt << 4) + l16][(w << 4) + (quad << 2)];
            float p = 0.f;
            if (w < qq) {
                p = fmaf(lo_f(uu.x), acc[dt][0], p);
                p = fmaf(hi_f(uu.x), acc[dt][1], p);
                p = fmaf(lo_f(uu.y), acc[dt][2], p);
                p = fmaf(hi_f(uu.y), acc[dt][3], p);
            } else {
                const int jb = (w << 4) + (quad << 2);
                if (jb + 0 <= i) p = fmaf(lo_f(uu.x), acc[dt][0], p);
                if (jb + 1 <= i) p = fmaf(hi_f(uu.x), acc[dt][1], p);
                if (jb + 2 <= i) p = fmaf(lo_f(uu.y), acc[dt][2], p);
                if (jb + 3 <= i) p = fmaf(hi_f(uu.y), acc[dt][3], p);
            }
            p += __shfl_xor(p, 16, 64);
            p += __shfl_xor(p, 32, 64);
            part[dt] = p;
        }
        const float sel = (quad == 0) ? part[0] : (quad == 1) ? part[1] : (quad == 2) ? part[2] : part[3];
        sY[qq][w][lane] = sel;

        #pragma unroll
        for (int off = 32; off; off >>= 1) zacc += __shfl_xor(zacc, off, 64);
        if (lane == 0) sZarr[qq][w] = zacc;
    }
    __syncthreads();                                       // bar2: all partials published

    // ---- final combine + store: wave w -> qq = w, d = lane ----
    {
        const int qq = w;
        const int i = (qq & 1) ? (16 * qq + 15 - ig) : (16 * qq + ig);
        float Z = 0.f;
        #pragma unroll
        for (int ww = 0; ww < 8; ++ww) Z += sZarr[qq][ww];
        float y = 0.f;
        #pragma unroll
        for (int ww = 0; ww < 8; ++ww) y += sY[qq][ww][lane];
        const int bb = bh >> 3, hh = bh & 7;
        Yb[((size_t)(bb * T + i) * C) + hh * HS + lane] = bfc(y / Z);
    }
}

// ---------------- K3: OUT = Yb @ Wc — B staged transposed-direct (2 barriers/iter), A in-register
__global__ __launch_bounds__(256) void outmm_kernel(
    const unsigned short* __restrict__ Ab, const float* __restrict__ Wc,
    float* __restrict__ OUT)
{
    __shared__ __align__(16) unsigned short Bs[64][72];
    const int m0 = blockIdx.y * 32, n0 = blockIdx.x * 64;
    const int tid = threadIdx.x;
    const int w = tid >> 6, lane = tid & 63, quad = lane >> 4, l16 = lane & 15;
    f32x4 acc[2];
    #pragma unroll
    for (int mt = 0; mt < 2; ++mt) acc[mt] = (f32x4){0.f, 0.f, 0.f, 0.f};

    const unsigned short* ar0 = Ab + (size_t)(m0 + l16) * 512;
    const unsigned short* ar1 = Ab + (size_t)(m0 + 16 + l16) * 512;

    for (int k0 = 0; k0 < 512; k0 += 64) {
        __syncthreads();
        #pragma unroll
        for (int it = 0; it < 4; ++it) {
            const int q = tid + it * 256;
            const int row = q >> 4, c4 = (q & 15) * 4;
            const float4 v = *(const float4*)&Wc[(size_t)(k0 + row) * 512 + n0 + c4];
            Bs[c4 + 0][row] = bfc(v.x); Bs[c4 + 1][row] = bfc(v.y);
            Bs[c4 + 2][row] = bfc(v.z); Bs[c4 + 3][row] = bfc(v.w);
        }
        __syncthreads();
        #pragma unroll
        for (int kt = 0; kt < 2; ++kt) {
            const int kb = k0 + kt * 32 + quad * 8;
            const bf16x8 b8 = *(const bf16x8*)&Bs[w * 16 + l16][kt * 32 + quad * 8];
            const bf16x8 a80 = *(const bf16x8*)(ar0 + kb);
            const bf16x8 a81 = *(const bf16x8*)(ar1 + kb);
            acc[0] = __builtin_amdgcn_mfma_f32_16x16x32_bf16(a80, b8, acc[0], 0, 0, 0);
            acc[1] = __builtin_amdgcn_mfma_f32_16x16x32_bf16(a81, b8, acc[1], 0, 0, 0);
        }
    }
    const int n = n0 + w * 16 + l16;
    #pragma unroll
    for (int mt = 0; mt < 2; ++mt)
        #pragma unroll
        for (int r = 0; r < 4; ++r) {
            const int mrow = m0 + mt * 16 + quad * 4 + r;
            OUT[(size_t)mrow * 512 + n] = acc[mt][r];
        }
}

extern "C" void kernel_launch(void* const* d_in, const int* in_sizes, int n_in,
                              void* d_out, int out_size, void* d_ws, size_t ws_size,
                              hipStream_t stream)
{
    const float* x   = (const float*)d_in[0];
    const float* Wp0 = (const float*)d_in[1];
    const float* Wp1 = (const float*)d_in[2];
    const float* Wp2 = (const float*)d_in[3];
    const float* Wv0 = (const float*)d_in[4];
    const float* Wv1 = (const float*)d_in[5];
    const float* Wc  = (const float*)d_in[6];
    float* out = (float*)d_out;

    char* w8 = (char*)d_ws;
    const size_t HB = 512 * 1024;
    unsigned short* p0b = (unsigned short*)(w8 + 0 * HB);
    unsigned short* p1b = (unsigned short*)(w8 + 1 * HB);
    unsigned short* V0T = (unsigned short*)(w8 + 2 * HB);
    unsigned short* V1T = (unsigned short*)(w8 + 3 * HB);
    unsigned short* Yb  = (unsigned short*)(w8 + 4 * HB);
    float*          rr  = (float*)        (w8 + 5 * HB);

    proj_kernel <<<dim3(8, 16, 3), 256, 0, stream>>>(x, Wp0, Wp1, Wp2, Wv0, Wv1,
                                                     p0b, p1b, V0T, V1T, rr);
    attn_kernel <<<dim3(512), 512, 0, stream>>>(p0b, p1b, rr, V0T, V1T, Yb);
    outmm_kernel<<<dim3(8, 16), 256, 0, stream>>>(Yb, Wc, out);
}

// Round 15
// 101.394 us; speedup vs baseline: 1.2463x; 1.2463x over previous
//
#include <hip/hip_runtime.h>
#include <hip/hip_bf16.h>
#include <math.h>

#define B 4
#define T 128
#define C 512
#define NH 8
#define HS 64
#define BH (B*NH)   // 32

typedef __attribute__((ext_vector_type(8))) short bf16x8;
typedef __attribute__((ext_vector_type(4))) float f32x4;

__device__ __forceinline__ unsigned short bfc(float x) {
    return __builtin_bit_cast(unsigned short, __float2bfloat16(x));
}
__device__ __forceinline__ unsigned int pk_bf16(float a, float b) {
    return (unsigned int)bfc(a) | ((unsigned int)bfc(b) << 16);
}
__device__ __forceinline__ float lo_f(unsigned int g) {
    return __builtin_bit_cast(float, g << 16);
}
__device__ __forceinline__ float hi_f(unsigned int g) {
    return __builtin_bit_cast(float, g & 0xffff0000u);
}

// ---------------- K1: p{0,1} = X @ Wp{0,1}; z==2 computes p2, emits rr + V1T only.
// Coalesced staging (global->LDS->strided LDS read); 3 barriers/k-iter (measured best).
// z==1 epilogue emits V0T = (p1@Wv0)^T; z==2 epilogue emits V1T = (p2@Wv1)^T.
__global__ __launch_bounds__(256) void proj_kernel(
    const float* __restrict__ X,
    const float* __restrict__ Wp0, const float* __restrict__ Wp1, const float* __restrict__ Wp2,
    const float* __restrict__ Wv0, const float* __restrict__ Wv1,
    unsigned short* __restrict__ p0b, unsigned short* __restrict__ p1b,
    unsigned short* __restrict__ V0T, unsigned short* __restrict__ V1T,
    float* __restrict__ rr)
{
    __shared__ __align__(16) unsigned short As[32][72];
    __shared__ __align__(16) unsigned short Bs[64][72];
    __shared__ float Ls[64][69];          // fp32 scratch for W-tile transpose
    __shared__ float sRS[4][32];
    const int z = blockIdx.z;
    const float* W = (z == 0) ? Wp0 : (z == 1) ? Wp1 : Wp2;
    const int m0 = blockIdx.y * 32, n0 = blockIdx.x * 64;
    const int tid = threadIdx.x;
    const int w = tid >> 6, lane = tid & 63, quad = lane >> 4, l16 = lane & 15;
    f32x4 acc[2];
    #pragma unroll
    for (int mt = 0; mt < 2; ++mt) acc[mt] = (f32x4){0.f, 0.f, 0.f, 0.f};

    for (int k0 = 0; k0 < 512; k0 += 64) {
        __syncthreads();
        {
            const int row = tid >> 3, c8 = (tid & 7) * 8;
            const float4 a = *(const float4*)&X[(size_t)(m0 + row) * 512 + k0 + c8];
            const float4 b = *(const float4*)&X[(size_t)(m0 + row) * 512 + k0 + c8 + 4];
            uint4 o;
            o.x = pk_bf16(a.x, a.y);
            o.y = pk_bf16(a.z, a.w);
            o.z = pk_bf16(b.x, b.y);
            o.w = pk_bf16(b.z, b.w);
            *(uint4*)&As[row][c8] = o;
        }
        #pragma unroll
        for (int it = 0; it < 4; ++it) {
            const int q = tid + it * 256;
            const int row = q >> 4, c4 = (q & 15) * 4;
            const float4 v = *(const float4*)&W[(size_t)(k0 + row) * 512 + n0 + c4];
            Ls[row][c4 + 0] = v.x; Ls[row][c4 + 1] = v.y;
            Ls[row][c4 + 2] = v.z; Ls[row][c4 + 3] = v.w;
        }
        __syncthreads();
        #pragma unroll
        for (int it = 0; it < 2; ++it) {
            const int q = tid + it * 256;
            const int nrow = q >> 3, k8 = (q & 7) * 8;
            uint4 o;
            o.x = pk_bf16(Ls[k8 + 0][nrow], Ls[k8 + 1][nrow]);
            o.y = pk_bf16(Ls[k8 + 2][nrow], Ls[k8 + 3][nrow]);
            o.z = pk_bf16(Ls[k8 + 4][nrow], Ls[k8 + 5][nrow]);
            o.w = pk_bf16(Ls[k8 + 6][nrow], Ls[k8 + 7][nrow]);
            *(uint4*)&Bs[nrow][k8] = o;
        }
        __syncthreads();
        #pragma unroll
        for (int kt = 0; kt < 2; ++kt) {
            const bf16x8 b8 = *(const bf16x8*)&Bs[w * 16 + l16][kt * 32 + quad * 8];
            #pragma unroll
            for (int mt = 0; mt < 2; ++mt) {
                const bf16x8 a8 = *(const bf16x8*)&As[mt * 16 + l16][kt * 32 + quad * 8];
                acc[mt] = __builtin_amdgcn_mfma_f32_16x16x32_bf16(a8, b8, acc[mt], 0, 0, 0);
            }
        }
    }

    // store p0/p1 (p2 never materialized)
    if (z != 2) {
        const int n = n0 + w * 16 + l16;
        const int h = n >> 6, d = n & 63;
        unsigned short* pz = (z == 0) ? p0b : p1b;
        #pragma unroll
        for (int mt = 0; mt < 2; ++mt) {
            #pragma unroll
            for (int r = 0; r < 4; ++r) {
                const int m = m0 + mt * 16 + quad * 4 + r;
                const int bb = m >> 7, t = m & 127;
                pz[((size_t)(bb * NH + h) * T + t) * HS + d] = bfc(acc[mt][r]);
            }
        }
    }
    if (z == 2) {
        // rr = rowsums of p2
        #pragma unroll
        for (int mt = 0; mt < 2; ++mt)
            #pragma unroll
            for (int r = 0; r < 4; ++r) {
                float v = acc[mt][r];
                v += __shfl_xor(v, 1, 64); v += __shfl_xor(v, 2, 64);
                v += __shfl_xor(v, 4, 64); v += __shfl_xor(v, 8, 64);
                if (l16 == 0) sRS[w][mt * 16 + quad * 4 + r] = v;
            }
        __syncthreads();
        if (tid < 32) {
            const float s = sRS[0][tid] + sRS[1][tid] + sRS[2][tid] + sRS[3][tid];
            const int m = m0 + tid, bb = m >> 7, tl = m & 127, h = n0 >> 6;
            rr[(bb * NH + h) * T + tl] = s;
        }
    }

    // ---- V-epilogue (z==1: V0T from p1; z==2: V1T from p2) ----
    if (z >= 1) {
        const float* Wv = (z == 1) ? Wv0 : Wv1;
        unsigned short* VT = (z == 1) ? V0T : V1T;
        __syncthreads();                                   // drain main-loop As/Bs reads
        // stage acc -> As as [t][d] bf16
        #pragma unroll
        for (int mt = 0; mt < 2; ++mt)
            #pragma unroll
            for (int r = 0; r < 4; ++r)
                As[mt * 16 + quad * 4 + r][w * 16 + l16] = bfc(acc[mt][r]);
        // stage Wv^T -> Bs as [d'][d] bf16
        #pragma unroll
        for (int it = 0; it < 4; ++it) {
            const int k = (tid >> 4) + it * 16;
            const int d0 = (tid & 15) * 4;
            const float4 wv = *(const float4*)&Wv[(size_t)k * 64 + d0];
            Bs[d0 + 0][k] = bfc(wv.x); Bs[d0 + 1][k] = bfc(wv.y);
            Bs[d0 + 2][k] = bfc(wv.z); Bs[d0 + 3][k] = bfc(wv.w);
        }
        __syncthreads();
        f32x4 vacc[2];
        #pragma unroll
        for (int mt = 0; mt < 2; ++mt) vacc[mt] = (f32x4){0.f, 0.f, 0.f, 0.f};
        #pragma unroll
        for (int kt = 0; kt < 2; ++kt) {
            const bf16x8 b8 = *(const bf16x8*)&Bs[w * 16 + l16][kt * 32 + quad * 8];
            #pragma unroll
            for (int mt = 0; mt < 2; ++mt) {
                const bf16x8 a8 = *(const bf16x8*)&As[mt * 16 + l16][kt * 32 + quad * 8];
                vacc[mt] = __builtin_amdgcn_mfma_f32_16x16x32_bf16(a8, b8, vacc[mt], 0, 0, 0);
            }
        }
        // D[m=t][n=d']: col=l16 -> d' = w*16+l16 ; row = quad*4+r -> t local; store VT[d'][t]
        const int h = n0 >> 6;
        const int bb = m0 >> 7, t0 = m0 & 127;
        const int bh = bb * NH + h;
        const int dp = w * 16 + l16;
        #pragma unroll
        for (int mt = 0; mt < 2; ++mt) {
            uint2 o;
            o.x = pk_bf16(vacc[mt][0], vacc[mt][1]);
            o.y = pk_bf16(vacc[mt][2], vacc[mt][3]);
            *(uint2*)&VT[((size_t)bh * HS + dp) * T + t0 + mt * 16 + quad * 4] = o;
        }
    }
}

// ---------------- K2: attention; 512 blocks x 512 threads; V0T/V1T precomputed -> 2 barriers total
__global__ __launch_bounds__(512, 4) void attn_kernel(
    const unsigned short* __restrict__ p0b, const unsigned short* __restrict__ p1b,
    const float* __restrict__ rr,
    const unsigned short* __restrict__ V0Tg, const unsigned short* __restrict__ V1Tg,
    unsigned short* __restrict__ Yb)
{
    __shared__ __align__(16) unsigned short sV0T[64][136];
    __shared__ __align__(16) unsigned short sV1T[64][136];
    __shared__ float sS[8][128];
    __shared__ float srr[128];
    __shared__ float sZarr[8][8];            // [qq][wave] Z partials
    __shared__ float sY[8][8][64];           // [qq][wave][d] y partials

    const int bid = blockIdx.x;
    const int bh = bid & (BH - 1);
    const int ig = bid >> 5;                 // 0..15
    const int tid = threadIdx.x;
    const int w = tid >> 6;                  // 0..7 : wave owns row-tile mt = w
    const int lane = tid & 63;
    const int quad = lane >> 4;
    const int l16 = lane & 15;

    if (tid < 128) srr[tid] = rr[bh * T + tid];

    // ---- copy V0T/V1T tiles (bh slice, [d][t] bf16, 16 KB each): 64 rows x 16 chunks ----
    #pragma unroll
    for (int it = 0; it < 2; ++it) {
        const int q = tid + it * 512;        // 0..1023
        const int row = q >> 4, c8 = (q & 15) * 8;
        *(uint4*)&sV0T[row][c8] = *(const uint4*)&V0Tg[((size_t)bh * HS + row) * T + c8];
        *(uint4*)&sV1T[row][c8] = *(const uint4*)&V1Tg[((size_t)bh * HS + row) * T + c8];
    }

    // ---- all 8 S rows (wave w covers j = w*16+l16) ----
    {
        const int qr = l16 & 7;
        const int irow = (qr & 1) ? (16 * qr + 15 - ig) : (16 * qr + ig);
        const unsigned short* ap = p0b + ((size_t)bh * T + irow) * HS + (quad << 3);
        const unsigned short* bp = p1b + (size_t)bh * T * HS + (quad << 3);
        f32x4 s0 = (f32x4){0.f, 0.f, 0.f, 0.f};
        #pragma unroll
        for (int kt = 0; kt < 2; ++kt) {
            const bf16x8 a8 = *(const bf16x8*)(ap + (kt << 5));
            const bf16x8 b0 = *(const bf16x8*)(bp + (size_t)((w << 4) + l16) * HS + (kt << 5));
            s0 = __builtin_amdgcn_mfma_f32_16x16x32_bf16(a8, b0, s0, 0, 0, 0);
        }
        if (quad < 2) {
            #pragma unroll
            for (int r = 0; r < 4; ++r)
                sS[quad * 4 + r][(w << 4) + l16] = s0[r] * 0.125f;
        }
    }
    // zero partial buffers
    #pragma unroll
    for (int it = 0; it < 8; ++it) ((float*)sY)[tid + it * 512] = 0.f;
    if (tid < 64) ((float*)sZarr)[tid] = 0.f;
    __syncthreads();                                       // bar1: everything staged

    const float L2E = 1.4426950408889634f;

    // ---- hoisted global mhat (upper bound via shift-invariance) ----
    float mhat;
    {
        float aS = 0.f;
        #pragma unroll
        for (int q = 0; q < 8; ++q) {
            aS = fmaxf(aS, fabsf(sS[q][lane]));
            aS = fmaxf(aS, fabsf(sS[q][64 + lane]));
        }
        float aR = fmaxf(fabsf(srr[lane]), fabsf(srr[64 + lane]));
        #pragma unroll
        for (int off = 32; off; off >>= 1) {
            aS = fmaxf(aS, __shfl_xor(aS, off, 64));
            aR = fmaxf(aR, __shfl_xor(aR, off, 64));
        }
        mhat = aS * aR;
    }
    const float bexp = -mhat * L2E;
    const int jrow = (w << 4) + l16;
    const int ktmax = w >> 1;

    // ---- BARRIER-FREE loop: wave w participates in qq >= w (mtmax == qq) ----
    for (int qq = 7; qq >= w; --qq) {
        const int i = (qq & 1) ? (16 * qq + 15 - ig) : (16 * qq + ig);
        const float aL = sS[qq][jrow] * L2E;
        const bool rowok = (jrow <= i);
        f32x4 acc[4];
        #pragma unroll
        for (int dt = 0; dt < 4; ++dt) acc[dt] = (f32x4){0.f, 0.f, 0.f, 0.f};
        float zacc = 0.f;

        for (int kt = 0; kt <= ktmax; ++kt) {
            const int kbase = (kt << 5) + (quad << 3);
            float rk[8];
            *(float4*)&rk[0] = *(const float4*)&srr[kbase];
            *(float4*)&rk[4] = *(const float4*)&srr[kbase + 4];
            const int dlim = rowok ? (jrow - kbase) : -1;
            float e[8];
            #pragma unroll
            for (int q = 0; q < 8; ++q) {
                const float ex = __builtin_amdgcn_exp2f(fmaf(aL, rk[q], bexp));
                e[q] = (q <= dlim) ? ex : 0.f;
                zacc += e[q];
            }
            uint4 o;
            o.x = pk_bf16(e[0], e[1]);
            o.y = pk_bf16(e[2], e[3]);
            o.z = pk_bf16(e[4], e[5]);
            o.w = pk_bf16(e[6], e[7]);
            const bf16x8 a8 = __builtin_bit_cast(bf16x8, o);
            #pragma unroll
            for (int dt = 0; dt < 4; ++dt) {
                const bf16x8 b8 = *(const bf16x8*)&sV1T[(dt << 4) + l16][(quad << 3) + (kt << 5)];
                acc[dt] = __builtin_amdgcn_mfma_f32_16x16x32_bf16(a8, b8, acc[dt], 0, 0, 0);
            }
        }

        // ---- epilogue: partial y over this wave's row-tile, all 4 d-tiles ----
        float part[4];
        #pragma unroll
        for (int dt = 0; dt < 4; ++dt) {
            const uint2 uu = *(const uint2*)&sV0T[(dt << 4) + l16][(w << 4) + (quad << 2)];
            float p = 0.f;
            if (w < qq) {
                p = fmaf(lo_f(uu.x), acc[dt][0], p);
                p = fmaf(hi_f(uu.x), acc[dt][1], p);
                p = fmaf(lo_f(uu.y), acc[dt][2], p);
                p = fmaf(hi_f(uu.y), acc[dt][3], p);
            } else {
                const int jb = (w << 4) + (quad << 2);
                if (jb + 0 <= i) p = fmaf(lo_f(uu.x), acc[dt][0], p);
                if (jb + 1 <= i) p = fmaf(hi_f(uu.x), acc[dt][1], p);
                if (jb + 2 <= i) p = fmaf(lo_f(uu.y), acc[dt][2], p);
                if (jb + 3 <= i) p = fmaf(hi_f(uu.y), acc[dt][3], p);
            }
            p += __shfl_xor(p, 16, 64);
            p += __shfl_xor(p, 32, 64);
            part[dt] = p;
        }
        const float sel = (quad == 0) ? part[0] : (quad == 1) ? part[1] : (quad == 2) ? part[2] : part[3];
        sY[qq][w][lane] = sel;

        #pragma unroll
        for (int off = 32; off; off >>= 1) zacc += __shfl_xor(zacc, off, 64);
        if (lane == 0) sZarr[qq][w] = zacc;
    }
    __syncthreads();                                       // bar2: all partials published

    // ---- final combine + store: wave w -> qq = w, d = lane ----
    {
        const int qq = w;
        const int i = (qq & 1) ? (16 * qq + 15 - ig) : (16 * qq + ig);
        float Z = 0.f;
        #pragma unroll
        for (int ww = 0; ww < 8; ++ww) Z += sZarr[qq][ww];
        float y = 0.f;
        #pragma unroll
        for (int ww = 0; ww < 8; ++ww) y += sY[qq][ww][lane];
        const int bb = bh >> 3, hh = bh & 7;
        Yb[((size_t)(bb * T + i) * C) + hh * HS + lane] = bfc(y / Z);
    }
}

// ---------------- K3: OUT = Yb @ Wc (bf16 A via LDS, fp32 W transposed on the fly, fp32 out)
__global__ __launch_bounds__(256) void outmm_kernel(
    const unsigned short* __restrict__ Ab, const float* __restrict__ Wc,
    float* __restrict__ OUT)
{
    __shared__ __align__(16) unsigned short As[32][72];
    __shared__ __align__(16) unsigned short Bs[64][72];
    __shared__ float Ls[64][69];
    const int m0 = blockIdx.y * 32, n0 = blockIdx.x * 64;
    const int tid = threadIdx.x;
    const int w = tid >> 6, lane = tid & 63, quad = lane >> 4, l16 = lane & 15;
    f32x4 acc[2];
    #pragma unroll
    for (int mt = 0; mt < 2; ++mt) acc[mt] = (f32x4){0.f, 0.f, 0.f, 0.f};
    for (int k0 = 0; k0 < 512; k0 += 64) {
        __syncthreads();
        {
            const int row = tid >> 3, c8 = (tid & 7) * 8;
            *(uint4*)&As[row][c8] = *(const uint4*)&Ab[(size_t)(m0 + row) * 512 + k0 + c8];
        }
        #pragma unroll
        for (int it = 0; it < 4; ++it) {
            const int q = tid + it * 256;
            const int row = q >> 4, c4 = (q & 15) * 4;
            const float4 v = *(const float4*)&Wc[(size_t)(k0 + row) * 512 + n0 + c4];
            Ls[row][c4 + 0] = v.x; Ls[row][c4 + 1] = v.y;
            Ls[row][c4 + 2] = v.z; Ls[row][c4 + 3] = v.w;
        }
        __syncthreads();
        #pragma unroll
        for (int it = 0; it < 2; ++it) {
            const int q = tid + it * 256;
            const int nrow = q >> 3, k8 = (q & 7) * 8;
            uint4 o;
            o.x = pk_bf16(Ls[k8 + 0][nrow], Ls[k8 + 1][nrow]);
            o.y = pk_bf16(Ls[k8 + 2][nrow], Ls[k8 + 3][nrow]);
            o.z = pk_bf16(Ls[k8 + 4][nrow], Ls[k8 + 5][nrow]);
            o.w = pk_bf16(Ls[k8 + 6][nrow], Ls[k8 + 7][nrow]);
            *(uint4*)&Bs[nrow][k8] = o;
        }
        __syncthreads();
        #pragma unroll
        for (int kt = 0; kt < 2; ++kt) {
            const bf16x8 b8 = *(const bf16x8*)&Bs[w * 16 + l16][kt * 32 + quad * 8];
            #pragma unroll
            for (int mt = 0; mt < 2; ++mt) {
                const bf16x8 a8 = *(const bf16x8*)&As[mt * 16 + l16][kt * 32 + quad * 8];
                acc[mt] = __builtin_amdgcn_mfma_f32_16x16x32_bf16(a8, b8, acc[mt], 0, 0, 0);
            }
        }
    }
    const int n = n0 + w * 16 + l16;
    #pragma unroll
    for (int mt = 0; mt < 2; ++mt)
        #pragma unroll
        for (int r = 0; r < 4; ++r) {
            const int mrow = m0 + mt * 16 + quad * 4 + r;
            OUT[(size_t)mrow * 512 + n] = acc[mt][r];
        }
}

extern "C" void kernel_launch(void* const* d_in, const int* in_sizes, int n_in,
                              void* d_out, int out_size, void* d_ws, size_t ws_size,
                              hipStream_t stream)
{
    const float* x   = (const float*)d_in[0];
    const float* Wp0 = (const float*)d_in[1];
    const float* Wp1 = (const float*)d_in[2];
    const float* Wp2 = (const float*)d_in[3];
    const float* Wv0 = (const float*)d_in[4];
    const float* Wv1 = (const float*)d_in[5];
    const float* Wc  = (const float*)d_in[6];
    float* out = (float*)d_out;

    char* w8 = (char*)d_ws;
    const size_t HB = 512 * 1024;
    unsigned short* p0b = (unsigned short*)(w8 + 0 * HB);
    unsigned short* p1b = (unsigned short*)(w8 + 1 * HB);
    unsigned short* V0T = (unsigned short*)(w8 + 2 * HB);
    unsigned short* V1T = (unsigned short*)(w8 + 3 * HB);
    unsigned short* Yb  = (unsigned short*)(w8 + 4 * HB);
    float*          rr  = (float*)        (w8 + 5 * HB);

    proj_kernel <<<dim3(8, 16, 3), 256, 0, stream>>>(x, Wp0, Wp1, Wp2, Wv0, Wv1,
                                                     p0b, p1b, V0T, V1T, rr);
    attn_kernel <<<dim3(512), 512, 0, stream>>>(p0b, p1b, rr, V0T, V1T, Yb);
    outmm_kernel<<<dim3(8, 16), 256, 0, stream>>>(Yb, Wc, out);
}